// Round 2
// baseline (243.068 us; speedup 1.0000x reference)
//
#include <hip/hip_runtime.h>
#include <stdint.h>
#include <stddef.h>

// MMD loss, fused: C = X·X^T gram (bf16 MFMA) + 5-kernel RBF epilogue + signed mean.
// N=8192 rows (4096 source + 4096 target), D=256.
//
// ws layout:
//   [0]     double total          (signed sum of kernel entries)
//   [8]     double sumsq          (sum of row sq-norms, bf16-rounded values)
//   [16]    double colsum[256]    (per-dim column sums of f32 inputs)
//   [2064]  float  coef           (-log2(e) / (16*bandwidth))
//   [4096]  float  sq[8192]       (row sq-norms of bf16-rounded rows)
//   [36864] ushort Xb[8192*256]   (bf16 copy of inputs)

#define N_TOT 8192
#define D_DIM 256
#define BS    4096
#define NB    64   // 8192 / 128 tiles per dim

typedef float  f32x4  __attribute__((ext_vector_type(4)));
typedef short  bf16x8 __attribute__((ext_vector_type(8)));

typedef __attribute__((address_space(1))) const unsigned int gas_u32;
typedef __attribute__((address_space(3))) unsigned int       lds_u32;

__device__ __forceinline__ unsigned short f2bf(float f) {
  unsigned u = __float_as_uint(f);
  u += 0x7fffu + ((u >> 16) & 1u);   // RNE; inputs are finite
  return (unsigned short)(u >> 16);
}
__device__ __forceinline__ float bf2f(unsigned short s) {
  return __uint_as_float(((unsigned)s) << 16);
}

// ---------------- prep: f32 -> bf16 copy, row sq-norms, sum of sq ----------------
__global__ void prep_kernel(const float* __restrict__ src, const float* __restrict__ tgt,
                            unsigned short* __restrict__ Xb, float* __restrict__ sq,
                            double* __restrict__ sumsq) {
  int tid  = threadIdx.x;
  int row  = blockIdx.x * 4 + (tid >> 6);  // one wave per row
  int lane = tid & 63;
  const float* rowp = (row < BS) ? (src + (size_t)row * D_DIM)
                                 : (tgt + (size_t)(row - BS) * D_DIM);
  float4 v = reinterpret_cast<const float4*>(rowp)[lane];
  ushort4 b;
  b.x = f2bf(v.x); b.y = f2bf(v.y); b.z = f2bf(v.z); b.w = f2bf(v.w);
  reinterpret_cast<ushort4*>(Xb + (size_t)row * D_DIM)[lane] = b;
  float fx = bf2f(b.x), fy = bf2f(b.y), fz = bf2f(b.z), fw = bf2f(b.w);
  float s = fx * fx + fy * fy + fz * fz + fw * fw;
  #pragma unroll
  for (int o = 32; o; o >>= 1) s += __shfl_down(s, o, 64);
  if (lane == 0) { sq[row] = s; atomicAdd(sumsq, (double)s); }
}

// ---------------- column sums (for ||sum_i x_i||^2 in the analytic l2-sum) ----------------
__global__ void colsum_kernel(const float* __restrict__ src, const float* __restrict__ tgt,
                              double* __restrict__ colsum) {
  int d  = threadIdx.x;           // 256 threads = one per column
  int r0 = blockIdx.x * 256;      // 32 blocks * 256 rows
  float s = 0.f;
  for (int r = 0; r < 256; ++r) {
    int row = r0 + r;
    const float* rowp = (row < BS) ? (src + (size_t)row * D_DIM)
                                   : (tgt + (size_t)(row - BS) * D_DIM);
    s += rowp[d];
  }
  atomicAdd(&colsum[d], (double)s);
}

// ---------------- bandwidth -> exp2 coefficient ----------------
__global__ void finbw_kernel(const double* __restrict__ sumsq, const double* __restrict__ colsum,
                             float* __restrict__ coef) {
  double s2 = 0.0;
  for (int d = 0; d < 256; ++d) { double c = colsum[d]; s2 += c * c; }
  double S  = 2.0 * (double)N_TOT * (*sumsq) - 2.0 * s2;   // sum of all pairwise sq dists
  double bw = S / ((double)N_TOT * (double)N_TOT - (double)N_TOT);
  bw = bw / 4.0;  // / KERNEL_MUL^(KERNEL_NUM//2) = 2^2
  // u = exp(-l2/(16 bw)) = exp2(l2 * coef); kernels = u + u^2 + u^4 + u^8 + u^16
  *coef = (float)(-1.4426950408889634 / (16.0 * bw));
}

// ---------------- fused gram + RBF epilogue ----------------
// Upper-triangular 128x128 tiles: 2080 blocks, 256 threads (4 waves, 64x64 each).
__launch_bounds__(256)
__global__ void gram_kernel(const unsigned short* __restrict__ Xb, const float* __restrict__ sq,
                            const float* __restrict__ coefp, double* __restrict__ total) {
  __shared__ __align__(16) unsigned short As[2][128 * 64];
  __shared__ __align__(16) unsigned short Bs[2][128 * 64];

  int tid = threadIdx.x;
  int w = tid >> 6, lane = tid & 63;

  // decode linear block id -> (bi, bj), bi <= bj
  int bi = 0, rem = (int)blockIdx.x;
  while (rem >= NB - bi) { rem -= NB - bi; ++bi; }
  int bj = bi + rem;

  float factor = ((bi < 32) == (bj < 32)) ? 1.f : -1.f;  // sign of the mean term
  if (bi != bj) factor *= 2.f;                            // symmetry weight

  const int browA = bi * 128, browB = bj * 128;

  // staging (global_load_lds, 16B/lane, linear LDS dest + inverse-swizzled source)
  const int lrow = lane >> 3;                 // row within 8-row group
  const int slot = (lane & 7) ^ lrow;         // pre-swizzled global 16B-slot
  // read-side addressing
  const int lo = lane & 15, hi = lane >> 4;
  const int xorv = (lane & 7) << 4;           // byte xor for swizzled ds_read (R&7 == lane&7)
  const int wr = w >> 1, wc = w & 1;

  f32x4 acc[4][4];
  #pragma unroll
  for (int m = 0; m < 4; ++m)
    #pragma unroll
    for (int n = 0; n < 4; ++n) acc[m][n] = (f32x4){0.f, 0.f, 0.f, 0.f};

  auto stage = [&](int buf, int kk) {
    #pragma unroll
    for (int q = 0; q < 4; ++q) {
      int rg  = (w * 4 + q) * 8;        // 8-row group this instruction fills
      int row = rg + lrow;
      const unsigned short* gA = Xb + ((size_t)(browA + row) * D_DIM + kk * 64 + slot * 8);
      const unsigned short* gB = Xb + ((size_t)(browB + row) * D_DIM + kk * 64 + slot * 8);
      __builtin_amdgcn_global_load_lds((gas_u32*)gA, (lds_u32*)(&As[buf][rg * 64]), 16, 0, 0);
      __builtin_amdgcn_global_load_lds((gas_u32*)gB, (lds_u32*)(&Bs[buf][rg * 64]), 16, 0, 0);
    }
  };

  stage(0, 0);
  __syncthreads();

  for (int kk = 0; kk < 4; ++kk) {
    int buf = kk & 1;
    if (kk < 3) stage(buf ^ 1, kk + 1);   // async prefetch; drained at the loop barrier
    const char* Abase = (const char*)&As[buf][0];
    const char* Bbase = (const char*)&Bs[buf][0];
    #pragma unroll
    for (int ks = 0; ks < 2; ++ks) {
      int cb = (ks * 64 + hi * 16) ^ xorv;   // swizzled byte-col within 128B row
      bf16x8 a[4], b[4];
      #pragma unroll
      for (int m = 0; m < 4; ++m) {
        int R = wr * 64 + m * 16 + lo;
        a[m] = *(const bf16x8*)(Abase + R * 128 + cb);
      }
      #pragma unroll
      for (int n = 0; n < 4; ++n) {
        int R = wc * 64 + n * 16 + lo;
        b[n] = *(const bf16x8*)(Bbase + R * 128 + cb);
      }
      #pragma unroll
      for (int m = 0; m < 4; ++m)
        #pragma unroll
        for (int n = 0; n < 4; ++n)
          acc[m][n] = __builtin_amdgcn_mfma_f32_16x16x32_bf16(a[m], b[n], acc[m][n], 0, 0, 0);
    }
    __syncthreads();
  }

  // epilogue: d2 = max(sq_i + sq_j - 2g, 0); sum_{i=0..4} exp(-d2/(bw*2^i)) = u+u^2+u^4+u^8+u^16
  float coef = *coefp;
  float sqj[4];
  #pragma unroll
  for (int n = 0; n < 4; ++n) sqj[n] = sq[browB + wc * 64 + n * 16 + lo];
  float psum = 0.f;
  #pragma unroll
  for (int m = 0; m < 4; ++m) {
    float sqi[4];
    #pragma unroll
    for (int r = 0; r < 4; ++r) sqi[r] = sq[browA + wr * 64 + m * 16 + hi * 4 + r];
    #pragma unroll
    for (int n = 0; n < 4; ++n) {
      #pragma unroll
      for (int r = 0; r < 4; ++r) {
        float g  = acc[m][n][r];
        float d2 = fmaxf(fmaf(-2.f, g, sqi[r] + sqj[n]), 0.f);
        float u  = __builtin_amdgcn_exp2f(d2 * coef);
        float u2 = u * u, u4 = u2 * u2, u8 = u4 * u4, u16 = u8 * u8;
        psum += u + u2 + u4 + u8 + u16;
      }
    }
  }
  #pragma unroll
  for (int o = 32; o; o >>= 1) psum += __shfl_down(psum, o, 64);
  if (lane == 0) atomicAdd(total, (double)(psum * factor));
}

// ---------------- finalize ----------------
__global__ void fin_kernel(const double* __restrict__ total, float* __restrict__ out) {
  out[0] = (float)(*total / ((double)BS * (double)BS));
}

extern "C" void kernel_launch(void* const* d_in, const int* in_sizes, int n_in,
                              void* d_out, int out_size, void* d_ws, size_t ws_size,
                              hipStream_t stream) {
  const float* src = (const float*)d_in[0];
  const float* tgt = (const float*)d_in[1];
  char* ws = (char*)d_ws;
  double* total  = (double*)(ws + 0);
  double* sumsq  = (double*)(ws + 8);
  double* colsum = (double*)(ws + 16);
  float*  coef   = (float*)(ws + 2064);
  float*  sq     = (float*)(ws + 4096);
  unsigned short* Xb = (unsigned short*)(ws + 36864);
  float* out = (float*)d_out;

  (void)hipMemsetAsync(d_ws, 0, 4096, stream);  // zero total/sumsq/colsum
  prep_kernel<<<2048, 256, 0, stream>>>(src, tgt, Xb, sq, sumsq);
  colsum_kernel<<<32, 256, 0, stream>>>(src, tgt, colsum);
  finbw_kernel<<<1, 1, 0, stream>>>(sumsq, colsum, coef);
  gram_kernel<<<2080, 256, 0, stream>>>(Xb, sq, coef, total);
  fin_kernel<<<1, 1, 0, stream>>>(total, out);
}

// Round 3
// 108.090 us; speedup vs baseline: 2.2488x; 2.2488x over previous
//
#include <hip/hip_runtime.h>
#include <stdint.h>
#include <stddef.h>

// MMD loss, fused: gram = X·X^T (bf16 MFMA, fragments direct from L2) +
// 5-kernel RBF epilogue + signed mean. N=8192 rows (4096 src + 4096 tgt), D=256.
//
// Round-3 structure: NO LDS staging in gram (K=256 is too short to pipeline a
// barrier'd LDS loop, and Xb (4 MB) is L2-resident — round-2 showed
// MfmaUtil 5.9% / 112 us with the staged version). Fragments load straight
// from global with the 16x16x32 lane mapping verified exact in round 2.
//
// ws layout:
//   [0]     double total          (signed sum of kernel entries)
//   [16]    double colsum[256]    (per-dim column sums of f32 inputs)
//   [2064]  float  coef           (-log2(e) / (16*bandwidth))
//   [4096]  float  sq[8192]       (row sq-norms of bf16-rounded rows)
//   [36864] ushort Xb[8192*256]   (bf16 copy of inputs)

#define N_TOT 8192
#define D_DIM 256
#define BS    4096
#define NB    64   // 8192 / 128 tiles per dim (2080 upper-tri tiles, %8==0)

typedef float  f32x4  __attribute__((ext_vector_type(4)));
typedef short  bf16x8 __attribute__((ext_vector_type(8)));

__device__ __forceinline__ unsigned short f2bf(float f) {
  unsigned u = __float_as_uint(f);
  u += 0x7fffu + ((u >> 16) & 1u);   // RNE; inputs are finite
  return (unsigned short)(u >> 16);
}
__device__ __forceinline__ float bf2f(unsigned short s) {
  return __uint_as_float(((unsigned)s) << 16);
}

// ---------------- prep: f32 -> bf16 copy + row sq-norms ----------------
__global__ void prep_kernel(const float* __restrict__ src, const float* __restrict__ tgt,
                            unsigned short* __restrict__ Xb, float* __restrict__ sq) {
  int tid  = threadIdx.x;
  int row  = blockIdx.x * 4 + (tid >> 6);  // one wave per row
  int lane = tid & 63;
  const float* rowp = (row < BS) ? (src + (size_t)row * D_DIM)
                                 : (tgt + (size_t)(row - BS) * D_DIM);
  float4 v = reinterpret_cast<const float4*>(rowp)[lane];
  ushort4 b;
  b.x = f2bf(v.x); b.y = f2bf(v.y); b.z = f2bf(v.z); b.w = f2bf(v.w);
  reinterpret_cast<ushort4*>(Xb + (size_t)row * D_DIM)[lane] = b;
  float fx = bf2f(b.x), fy = bf2f(b.y), fz = bf2f(b.z), fw = bf2f(b.w);
  float s = fx * fx + fy * fy + fz * fz + fw * fw;
  #pragma unroll
  for (int o = 32; o; o >>= 1) s += __shfl_down(s, o, 64);
  if (lane == 0) sq[row] = s;
}

// ---------------- column sums (for ||sum_i x_i||^2 in the analytic l2-sum) ----------------
__global__ void colsum_kernel(const float* __restrict__ src, const float* __restrict__ tgt,
                              double* __restrict__ colsum) {
  int d  = threadIdx.x;           // 256 threads = one per column
  int r0 = blockIdx.x * 32;       // 256 blocks * 32 rows
  float s = 0.f;
  #pragma unroll
  for (int r = 0; r < 32; ++r) {
    int row = r0 + r;
    const float* rowp = (row < BS) ? (src + (size_t)row * D_DIM)
                                   : (tgt + (size_t)(row - BS) * D_DIM);
    s += rowp[d];
  }
  atomicAdd(&colsum[d], (double)s);
}

// ---------------- bandwidth -> exp2 coefficient (1 block, 256 thr) ----------------
__global__ void finbw_kernel(const float* __restrict__ sq, const double* __restrict__ colsum,
                             float* __restrict__ coef) {
  int t = threadIdx.x, w = t >> 6, lane = t & 63;
  double s = 0.0;
  #pragma unroll
  for (int i = 0; i < 32; ++i) s += (double)sq[t + i * 256];
  double c  = colsum[t];
  double s2 = c * c;
  #pragma unroll
  for (int o = 32; o; o >>= 1) { s += __shfl_down(s, o, 64); s2 += __shfl_down(s2, o, 64); }
  __shared__ double rs[4], rs2[4];
  if (lane == 0) { rs[w] = s; rs2[w] = s2; }
  __syncthreads();
  if (t == 0) {
    double S1 = rs[0] + rs[1] + rs[2] + rs[3];
    double S2 = rs2[0] + rs2[1] + rs2[2] + rs2[3];
    double S  = 2.0 * (double)N_TOT * S1 - 2.0 * S2;   // sum of all pairwise sq dists
    double bw = S / ((double)N_TOT * (double)N_TOT - (double)N_TOT);
    bw = bw / 4.0;  // / KERNEL_MUL^(KERNEL_NUM//2)
    // u = exp(-l2/(16 bw)) = exp2(l2 * coef); kernels = u+u^2+u^4+u^8+u^16
    *coef = (float)(-1.4426950408889634 / (16.0 * bw));
  }
}

// ---------------- fused gram + RBF epilogue, no LDS staging ----------------
// Upper-tri 128x128 tiles: 2080 blocks, 4 waves, each wave one 64x64 quadrant.
__launch_bounds__(256, 3)
__global__ void gram_kernel(const unsigned short* __restrict__ Xb, const float* __restrict__ sq,
                            const float* __restrict__ coefp, double* __restrict__ total) {
  int tid = threadIdx.x;
  int w = tid >> 6, lane = tid & 63;
  const int lo = lane & 15, hi = lane >> 4;
  const int wr = w >> 1, wc = w & 1;

  // XCD-contiguous swizzle (2080 % 8 == 0): XCD c gets decoded ids [c*260,(c+1)*260)
  int orig = (int)blockIdx.x;
  int id   = (orig & 7) * (2080 / 8) + (orig >> 3);

  // decode linear tile id -> (bi, bj), bi <= bj
  int bi = 0, rem = id;
  while (rem >= NB - bi) { rem -= NB - bi; ++bi; }
  int bj = bi + rem;

  float factor = ((bi < 32) == (bj < 32)) ? 1.f : -1.f;  // sign of the mean term
  if (bi != bj) factor *= 2.f;                            // symmetry weight

  const int browA = bi * 128, browB = bj * 128;

  // per-lane fragment base addresses (verified mapping: row = lane&15, k-group = lane>>4)
  const char* pA = (const char*)Xb + ((size_t)(browA + wr * 64 + lo) * D_DIM + hi * 8) * 2;
  const char* pB = (const char*)Xb + ((size_t)(browB + wc * 64 + lo) * D_DIM + hi * 8) * 2;
  // row stride 512 B; m-step = 16 rows = 8192 B; k-chunk step = 32 elems = 64 B

  f32x4 acc[4][4];
  #pragma unroll
  for (int m = 0; m < 4; ++m)
    #pragma unroll
    for (int n = 0; n < 4; ++n) acc[m][n] = (f32x4){0.f, 0.f, 0.f, 0.f};

  bf16x8 a0[4], b0[4], a1[4], b1[4];

  auto load = [&](bf16x8* a, bf16x8* b, int kc) {
    #pragma unroll
    for (int m = 0; m < 4; ++m) a[m] = *(const bf16x8*)(pA + m * 8192 + kc * 64);
    #pragma unroll
    for (int n = 0; n < 4; ++n) b[n] = *(const bf16x8*)(pB + n * 8192 + kc * 64);
  };
  auto mm = [&](bf16x8* a, bf16x8* b) {
    #pragma unroll
    for (int m = 0; m < 4; ++m)
      #pragma unroll
      for (int n = 0; n < 4; ++n)
        acc[m][n] = __builtin_amdgcn_mfma_f32_16x16x32_bf16(a[m], b[n], acc[m][n], 0, 0, 0);
  };

  load(a0, b0, 0);
  #pragma unroll
  for (int kc = 0; kc < 8; ++kc) {       // D=256 -> 8 chunks of K=32
    if (kc & 1) {
      if (kc < 7) load(a0, b0, kc + 1);
      mm(a1, b1);
    } else {
      if (kc < 7) load(a1, b1, kc + 1);
      mm(a0, b0);
    }
  }

  // epilogue: d2 = max(sq_i + sq_j - 2g, 0); kernels = u+u^2+u^4+u^8+u^16, u=exp2(d2*coef)
  float coef = *coefp;
  float sqj[4];
  #pragma unroll
  for (int n = 0; n < 4; ++n) sqj[n] = sq[browB + wc * 64 + n * 16 + lo];
  float psum = 0.f;
  #pragma unroll
  for (int m = 0; m < 4; ++m) {
    float sqi[4];
    #pragma unroll
    for (int r = 0; r < 4; ++r) sqi[r] = sq[browA + wr * 64 + m * 16 + hi * 4 + r];
    #pragma unroll
    for (int n = 0; n < 4; ++n) {
      #pragma unroll
      for (int r = 0; r < 4; ++r) {
        float g  = acc[m][n][r];
        float d2 = fmaxf(fmaf(-2.f, g, sqi[r] + sqj[n]), 0.f);
        float u  = __builtin_amdgcn_exp2f(d2 * coef);
        float u2 = u * u, u4 = u2 * u2, u8 = u4 * u4, u16 = u8 * u8;
        psum += u + u2 + u4 + u8 + u16;
      }
    }
  }
  #pragma unroll
  for (int o = 32; o; o >>= 1) psum += __shfl_down(psum, o, 64);
  __shared__ float wred[4];
  if (lane == 0) wred[w] = psum;
  __syncthreads();
  if (tid == 0)
    atomicAdd(total, (double)((wred[0] + wred[1] + wred[2] + wred[3]) * factor));
}

// ---------------- finalize ----------------
__global__ void fin_kernel(const double* __restrict__ total, float* __restrict__ out) {
  out[0] = (float)(*total / ((double)BS * (double)BS));
}

extern "C" void kernel_launch(void* const* d_in, const int* in_sizes, int n_in,
                              void* d_out, int out_size, void* d_ws, size_t ws_size,
                              hipStream_t stream) {
  const float* src = (const float*)d_in[0];
  const float* tgt = (const float*)d_in[1];
  char* ws = (char*)d_ws;
  double* total  = (double*)(ws + 0);
  double* colsum = (double*)(ws + 16);
  float*  coef   = (float*)(ws + 2064);
  float*  sq     = (float*)(ws + 4096);
  unsigned short* Xb = (unsigned short*)(ws + 36864);
  float* out = (float*)d_out;

  (void)hipMemsetAsync(d_ws, 0, 4096, stream);  // zero total/colsum
  prep_kernel<<<2048, 256, 0, stream>>>(src, tgt, Xb, sq);
  colsum_kernel<<<256, 256, 0, stream>>>(src, tgt, colsum);
  finbw_kernel<<<1, 256, 0, stream>>>(sq, colsum, coef);
  gram_kernel<<<2080, 256, 0, stream>>>(Xb, sq, coef, total);
  fin_kernel<<<1, 1, 0, stream>>>(total, out);
}

// Round 4
// 106.592 us; speedup vs baseline: 2.2804x; 1.0141x over previous
//
#include <hip/hip_runtime.h>
#include <stdint.h>
#include <stddef.h>

// MMD loss, fused: gram = X·X^T (bf16 MFMA) + 5-kernel RBF epilogue + signed mean.
// N=8192 rows (4096 src + 4096 tgt), D=256.
//
// Round-4 structure: NO LDS. Xb is stored PRE-TRANSPOSED into MFMA fragment
// order, so every fragment load is a fully-coalesced 1KB/wave dwordx4 from
// L2. Round-3 evidence: row-scattered fragment loads (16 segments/instr)
// bottlenecked the VMEM addresser at MfmaUtil 7.8%.
//
// Fragment layout: elem(r,k) at  (r>>4)*4096 + (k>>3)*128 + (r&15)*8 + (k&7)
// -> lane(lo,hi) fragment base byte = rowgroup*8192 + (kc*4+hi)*256 + lo*16
//    (contiguous across the 64 lanes).
//
// ws layout:
//   [0]     double total          (signed sum of kernel entries)
//   [8]     int    cnt_colsum     (ticket for colsum->bandwidth fusion)
//   [12]    int    cnt_gram       (ticket for gram->finalize fusion)
//   [16]    double colsum[256]
//   [2064]  float  coef           (-log2(e) / (16*bandwidth))
//   [4096]  float  sq[8192]       (row sq-norms of bf16-rounded rows)
//   [36864] ushort Xbt[8192*256]  (bf16, fragment-transposed)

#define N_TOT 8192
#define D_DIM 256
#define BS    4096
#define NB    64   // 128-row tiles per dim; 2080 upper-tri tiles (%8==0)

typedef float  f32x4  __attribute__((ext_vector_type(4)));
typedef short  bf16x8 __attribute__((ext_vector_type(8)));

__device__ __forceinline__ unsigned short f2bf(float f) {
  unsigned u = __float_as_uint(f);
  u += 0x7fffu + ((u >> 16) & 1u);   // RNE; inputs are finite
  return (unsigned short)(u >> 16);
}
__device__ __forceinline__ float bf2f(unsigned short s) {
  return __uint_as_float(((unsigned)s) << 16);
}

// ---------------- prep: f32 -> bf16 fragment-transposed copy + row sq-norms ----------------
__global__ void prep_kernel(const float* __restrict__ src, const float* __restrict__ tgt,
                            unsigned short* __restrict__ Xbt, float* __restrict__ sq) {
  int tid  = threadIdx.x;
  int row  = blockIdx.x * 4 + (tid >> 6);  // one wave per row
  int lane = tid & 63;
  const float* rowp = (row < BS) ? (src + (size_t)row * D_DIM)
                                 : (tgt + (size_t)(row - BS) * D_DIM);
  float4 v = reinterpret_cast<const float4*>(rowp)[lane];   // cols k..k+3, k = lane*4
  ushort4 b;
  b.x = f2bf(v.x); b.y = f2bf(v.y); b.z = f2bf(v.z); b.w = f2bf(v.w);
  int k = lane * 4;
  size_t off = ((size_t)(row >> 4)) * 4096 + (size_t)(k >> 3) * 128
             + (size_t)((row & 15) * 8) + (k & 7);          // k..k+3 stay contiguous
  *reinterpret_cast<ushort4*>(Xbt + off) = b;
  float fx = bf2f(b.x), fy = bf2f(b.y), fz = bf2f(b.z), fw = bf2f(b.w);
  float s = fx * fx + fy * fy + fz * fz + fw * fw;
  #pragma unroll
  for (int o = 32; o; o >>= 1) s += __shfl_down(s, o, 64);
  if (lane == 0) sq[row] = s;
}

// ---------------- column sums + (last block) bandwidth coefficient ----------------
__global__ void colsum_kernel(const float* __restrict__ src, const float* __restrict__ tgt,
                              double* __restrict__ colsum, const float* __restrict__ sq,
                              int* __restrict__ cnt, float* __restrict__ coef) {
  int d  = threadIdx.x;           // 256 threads = one per column
  int r0 = blockIdx.x * 32;       // 256 blocks * 32 rows
  float s = 0.f;
  #pragma unroll
  for (int r = 0; r < 32; ++r) {
    int row = r0 + r;
    const float* rowp = (row < BS) ? (src + (size_t)row * D_DIM)
                                   : (tgt + (size_t)(row - BS) * D_DIM);
    s += rowp[d];
  }
  atomicAdd(&colsum[d], (double)s);
  __threadfence();
  __shared__ int ticket;
  if (d == 0) ticket = atomicAdd(cnt, 1);
  __syncthreads();
  if (ticket != 255) return;

  // last block: compute coef (all colsum atomics are globally visible; read atomically)
  int t = d, w = t >> 6, lane = t & 63;
  double s1 = 0.0;
  #pragma unroll
  for (int i = 0; i < 32; ++i) s1 += (double)sq[t + i * 256];
  double c  = atomicAdd(&colsum[t], 0.0);   // coherent cross-XCD read
  double s2 = c * c;
  #pragma unroll
  for (int o = 32; o; o >>= 1) { s1 += __shfl_down(s1, o, 64); s2 += __shfl_down(s2, o, 64); }
  __shared__ double rs[4], rs2[4];
  if (lane == 0) { rs[w] = s1; rs2[w] = s2; }
  __syncthreads();
  if (t == 0) {
    double S1 = rs[0] + rs[1] + rs[2] + rs[3];
    double S2 = rs2[0] + rs2[1] + rs2[2] + rs2[3];
    double S  = 2.0 * (double)N_TOT * S1 - 2.0 * S2;   // sum of all pairwise sq dists
    double bw = (S / ((double)N_TOT * (double)N_TOT - (double)N_TOT)) / 4.0;
    // u = exp(-l2/(16 bw)) = exp2(l2 * coef); kernels = u+u^2+u^4+u^8+u^16
    *coef = (float)(-1.4426950408889634 / (16.0 * bw));
  }
}

// ---------------- fused gram + RBF epilogue + (last block) finalize ----------------
// Upper-tri 128x128 tiles: 2080 blocks, 4 waves, each wave one 64x64 quadrant.
__launch_bounds__(256, 3)
__global__ void gram_kernel(const unsigned short* __restrict__ Xbt, const float* __restrict__ sq,
                            const float* __restrict__ coefp, double* __restrict__ total,
                            int* __restrict__ cnt, float* __restrict__ out) {
  int tid = threadIdx.x;
  int w = tid >> 6, lane = tid & 63;
  const int lo = lane & 15, hi = lane >> 4;
  const int wr = w >> 1, wc = w & 1;

  // XCD-contiguous swizzle (2080 % 8 == 0)
  int orig = (int)blockIdx.x;
  int id   = (orig & 7) * (2080 / 8) + (orig >> 3);

  // decode linear tile id -> (bi, bj), bi <= bj
  int bi = 0, rem = id;
  while (rem >= NB - bi) { rem -= NB - bi; ++bi; }
  int bj = bi + rem;

  float factor = ((bi < 32) == (bj < 32)) ? 1.f : -1.f;  // sign of the mean term
  if (bi != bj) factor *= 2.f;                            // symmetry weight

  // fragment base (coalesced layout): rowgroup*8192 + (kc*4+hi)*256 + lo*16 bytes
  const char* pA = (const char*)Xbt + (size_t)(bi * 8 + wr * 4) * 8192 + (hi * 256 + lo * 16);
  const char* pB = (const char*)Xbt + (size_t)(bj * 8 + wc * 4) * 8192 + (hi * 256 + lo * 16);
  // m-step = +8192 B (one 16-row group); kc-step = +1024 B

  f32x4 acc[4][4];
  #pragma unroll
  for (int m = 0; m < 4; ++m)
    #pragma unroll
    for (int n = 0; n < 4; ++n) acc[m][n] = (f32x4){0.f, 0.f, 0.f, 0.f};

  bf16x8 a0[4], b0[4], a1[4], b1[4];

  auto load = [&](bf16x8* a, bf16x8* b, int kc) {
    #pragma unroll
    for (int m = 0; m < 4; ++m) a[m] = *(const bf16x8*)(pA + m * 8192 + kc * 1024);
    #pragma unroll
    for (int n = 0; n < 4; ++n) b[n] = *(const bf16x8*)(pB + n * 8192 + kc * 1024);
  };
  auto mm = [&](bf16x8* a, bf16x8* b) {
    #pragma unroll
    for (int m = 0; m < 4; ++m)
      #pragma unroll
      for (int n = 0; n < 4; ++n)
        acc[m][n] = __builtin_amdgcn_mfma_f32_16x16x32_bf16(a[m], b[n], acc[m][n], 0, 0, 0);
  };

  load(a0, b0, 0);
  #pragma unroll
  for (int kc = 0; kc < 8; ++kc) {       // D=256 -> 8 chunks of K=32
    if (kc & 1) {
      if (kc < 7) load(a0, b0, kc + 1);
      mm(a1, b1);
    } else {
      if (kc < 7) load(a1, b1, kc + 1);
      mm(a0, b0);
    }
  }

  // epilogue: d2 = max(sq_i + sq_j - 2g, 0); kernels = u+u^2+u^4+u^8+u^16, u=exp2(d2*coef)
  float coef = *coefp;
  float sqj[4];
  #pragma unroll
  for (int n = 0; n < 4; ++n) sqj[n] = sq[bj * 128 + wc * 64 + n * 16 + lo];
  float psum = 0.f;
  #pragma unroll
  for (int m = 0; m < 4; ++m) {
    float sqi[4];
    #pragma unroll
    for (int r = 0; r < 4; ++r) sqi[r] = sq[bi * 128 + wr * 64 + m * 16 + hi * 4 + r];
    #pragma unroll
    for (int n = 0; n < 4; ++n) {
      #pragma unroll
      for (int r = 0; r < 4; ++r) {
        float g  = acc[m][n][r];
        float d2 = fmaxf(fmaf(-2.f, g, sqi[r] + sqj[n]), 0.f);
        float u  = __builtin_amdgcn_exp2f(d2 * coef);
        float u2 = u * u, u4 = u2 * u2, u8 = u4 * u4, u16 = u8 * u8;
        psum += (u + u2) + (u4 + u8) + u16;
      }
    }
  }
  #pragma unroll
  for (int o = 32; o; o >>= 1) psum += __shfl_down(psum, o, 64);
  __shared__ float wred[4];
  if (lane == 0) wred[w] = psum;
  __syncthreads();
  if (tid == 0) {
    atomicAdd(total, (double)((wred[0] + wred[1] + wred[2] + wred[3]) * factor));
    __threadfence();
    int ticket = atomicAdd(cnt, 1);
    if (ticket == 2079) {
      double t = atomicAdd(total, 0.0);   // coherent read of the full sum
      out[0] = (float)(t / ((double)BS * (double)BS));
    }
  }
}

extern "C" void kernel_launch(void* const* d_in, const int* in_sizes, int n_in,
                              void* d_out, int out_size, void* d_ws, size_t ws_size,
                              hipStream_t stream) {
  const float* src = (const float*)d_in[0];
  const float* tgt = (const float*)d_in[1];
  char* ws = (char*)d_ws;
  double* total   = (double*)(ws + 0);
  int*    cnt_cs  = (int*)(ws + 8);
  int*    cnt_gr  = (int*)(ws + 12);
  double* colsum  = (double*)(ws + 16);
  float*  coef    = (float*)(ws + 2064);
  float*  sq      = (float*)(ws + 4096);
  unsigned short* Xbt = (unsigned short*)(ws + 36864);
  float* out = (float*)d_out;

  (void)hipMemsetAsync(d_ws, 0, 4096, stream);  // zero total/tickets/colsum
  prep_kernel<<<2048, 256, 0, stream>>>(src, tgt, Xbt, sq);
  colsum_kernel<<<256, 256, 0, stream>>>(src, tgt, colsum, sq, cnt_cs, coef);
  gram_kernel<<<2080, 256, 0, stream>>>(Xbt, sq, coef, total, cnt_gr, out);
}